// Round 1
// baseline (116.245 us; speedup 1.0000x reference)
//
#include <hip/hip_runtime.h>
#include <hip/hip_bf16.h>

#define NB   64
#define SL   1024
#define EMB  128
#define NSK  1000
#define TI   64
#define NS   2     // split of i-tiles per j-tile

// bf16 table layout in ws (elements):
#define AI_OFF 0
#define BI_OFF 256000
#define AS_OFF 512000
#define BS_OFF 640000
#define TB_ELEMS 768000
#define ACC_BYTE_OFF (TB_ELEMS * 2)   // acc: [NS][NB][SL] float = 512 KB

using short8  = __attribute__((ext_vector_type(8))) short;
using floatx4 = __attribute__((ext_vector_type(4))) float;

// log5(x) = log2(x) * INV_LOG2_5
#define INV_LOG2_5 0.43067655807339306f

__device__ inline unsigned cvt2(float x, float y) {
    float2 f; f.x = x; f.y = y;
    __hip_bfloat162 h = __float22bfloat162_rn(f);
    unsigned u; __builtin_memcpy(&u, &h, sizeof(u));
    return u;
}

// ---- one-time fp32 -> bf16 table conversion (8 elems/thread) ----
extern "C" __global__ __launch_bounds__(256)
void cvt_tables(const float* __restrict__ ai, const float* __restrict__ bi,
                const float* __restrict__ as, const float* __restrict__ bs,
                unsigned short* __restrict__ dst)
{
    const int t = blockIdx.x * 256 + threadIdx.x;   // 96000 threads
    const long e = (long)t * 8;
    const float* src;
    if      (e < 256000) src = ai + e;
    else if (e < 512000) src = bi + (e - 256000);
    else if (e < 640000) src = as + (e - 512000);
    else                 src = bs + (e - 640000);
    float4 f0 = *(const float4*)src;
    float4 f1 = *(const float4*)(src + 4);
    uint4 pk;
    pk.x = cvt2(f0.x, f0.y); pk.y = cvt2(f0.z, f0.w);
    pk.z = cvt2(f1.x, f1.y); pk.w = cvt2(f1.z, f1.w);
    *(uint4*)(dst + e) = pk;
}

// exact fp32 path for duplicate-timestamp pairs (dt==0, i<j):
// contribution = alpha_dot * exp(beta' * 14.306765580733931)   [= -log(1e-10)/log(5)]
__device__ float fixup_pair(const float* __restrict__ air,
                            const float* __restrict__ bir,
                            const float* __restrict__ asr,
                            const float* __restrict__ bsr) {
    float da = 0.f, db = 0.f;
#pragma unroll 8
    for (int k = 0; k < EMB; k += 4) {
        float4 a  = *(const float4*)(air + k);
        float4 s  = *(const float4*)(asr + k);
        float4 bq = *(const float4*)(bir + k);
        float4 tt = *(const float4*)(bsr + k);
        da += a.x * s.x + a.y * s.y + a.z * s.z + a.w * s.w;
        db += bq.x * tt.x + bq.y * tt.y + bq.z * tt.z + bq.w * tt.w;
    }
    float beta = fminf(fmaxf(db + 1.f, 0.f), 10.f);
    return da * __expf(beta * 14.30676558073393f);
}

// ---- staging: each thread carries one 64B quarter-row of one matrix ----
struct Stage { uint4 a0, a1, a2, a3; };

__device__ __forceinline__ Stage stage_load(const int* __restrict__ binp,
                                            const unsigned short* __restrict__ tb,
                                            int ib, int row, int m, int sq)
{
    const int irow  = ib + row;
    const int ski   = binp[irow];
    const int li    = binp[2 * SL + irow];
    const long intr = ski + (long)li * NSK;
    const unsigned short* src = tb + (m ? BI_OFF : AI_OFF) + intr * EMB + sq * 32;
    Stage s;
    s.a0 = *(const uint4*)(src);
    s.a1 = *(const uint4*)(src + 8);
    s.a2 = *(const uint4*)(src + 16);
    s.a3 = *(const uint4*)(src + 24);
    return s;
}

// LDS layout: [mat 2][row 32][256B], 16B chunk c of row r stored at
// perm(c) = ((c>>1)&7 | (c&1)<<3) ^ (r&7)  -> conflict-free ds_write_b128
// AND ds_read_b128 (any 8 consecutive lanes hit 8 distinct 16B slots).
__device__ __forceinline__ void stage_write(char* buf, int wbase, const Stage& s) {
    *(uint4*)(buf + wbase)              = s.a0;   // chunk 4sq   -> slot (2sq)^r7
    *(uint4*)(buf + wbase + 128)        = s.a1;   // chunk 4sq+1 -> same slot, hi half
    *(uint4*)(buf + (wbase ^ 16))       = s.a2;   // chunk 4sq+2 -> slot ((2sq)^r7)^1
    *(uint4*)(buf + (wbase ^ 16) + 128) = s.a3;   // chunk 4sq+3 -> hi half
}

__device__ __forceinline__ float phase_compute(const char* __restrict__ buf,
                                               const int* __restrict__ binp,
                                               const short8 bfa[4], const short8 bfb[4],
                                               const int roff[4],
                                               int ib, int tj, int quad)
{
    float psum = 0.f;
#pragma unroll
    for (int isub = 0; isub < 2; ++isub) {
        floatx4 aa = {0.f, 0.f, 0.f, 0.f};
        floatx4 bb = {1.f, 1.f, 1.f, 1.f};   // folds the "+1.0" into the accumulator
#pragma unroll
        for (int ks = 0; ks < 4; ++ks) {
            short8 av = *(const short8*)(buf + isub * 4096 + roff[ks]);
            short8 bv = *(const short8*)(buf + 8192 + isub * 4096 + roff[ks]);
            aa = __builtin_amdgcn_mfma_f32_16x16x32_bf16(av, bfa[ks], aa, 0, 0, 0);
            bb = __builtin_amdgcn_mfma_f32_16x16x32_bf16(bv, bfb[ks], bb, 0, 0, 0);
        }
        const int ibase = ib + isub * 16 + quad * 4;   // C row = quad*4+reg
        const int4 t4 = *(const int4*)(binp + 3 * SL + ibase);
#pragma unroll
        for (int rr = 0; rr < 4; ++rr) {
            const int ti = (rr == 0) ? t4.x : (rr == 1) ? t4.y : (rr == 2) ? t4.z : t4.w;
            const int dt = tj - ti;
            // sorted times => (i<j && dt>0) <=> dt>0 ; dt==0 (dup) handled in finalize
            float lc  = __log2f((float)dt);                       // junk if dt<=0, discarded
            float nb  = fminf(fmaxf(bb[rr], 0.f), 10.f) * (-INV_LOG2_5);
            float arg = (dt > 0) ? nb * lc : -__builtin_inff();
            psum += aa[rr] * __builtin_amdgcn_exp2f(arg);
        }
    }
    return psum;
}

extern "C" __global__ __launch_bounds__(256, 4)
void hawkes_main(const int*   __restrict__ inp,     // (B,4,L) int32
                 const unsigned short* __restrict__ tb,  // bf16 tables
                 float*       __restrict__ acc)     // [NS][NB][SL] partials
{
    __shared__ uint4 lds4[2048];                    // 2 bufs x (2 mats x 32 rows x 256B)
    char* ldsc = (char*)lds4;

    const int bid  = blockIdx.x;
    const int b    = bid & (NB - 1);
    const int r    = bid >> 6;                 // 0..31
    const int jt   = 15 - (r >> 1);            // heavy tiles dispatch first
    const int s    = r & 1;
    const int tid  = threadIdx.x;
    const int w    = tid >> 6;                 // wave -> 16-j strip
    const int l    = tid & 63;
    const int quad = l >> 4;
    const int col  = l & 15;

    const int* __restrict__ binp = inp + b * 4 * SL;

    const int jlane = jt * TI + w * 16 + col;
    const int sk_j  = binp[jlane];
    const int tj    = binp[3 * SL + jlane];

    // ---- B fragments (skill rows of this lane's j), fixed for whole block ----
    short8 bfa[4], bfb[4];
    {
        const unsigned short* asr16 = tb + AS_OFF + (long)sk_j * EMB + quad * 8;
        const unsigned short* bsr16 = tb + BS_OFF + (long)sk_j * EMB + quad * 8;
#pragma unroll
        for (int ks = 0; ks < 4; ++ks) {
            bfa[ks] = *(const short8*)(asr16 + ks * 32);
            bfb[ks] = *(const short8*)(bsr16 + ks * 32);
        }
    }

    // ---- lane-invariant swizzled read offsets (chunk c = 4ks+quad) ----
    int roff[4];
    {
        const int qh = quad >> 1, ql = quad & 1, c7 = col & 7;
#pragma unroll
        for (int ks = 0; ks < 4; ++ks)
            roff[ks] = col * 256 + ql * 128 + (((2 * ks + qh) ^ c7) << 4);
    }

    // ---- staging role: 256 threads cover 2 mats x 32 rows x 4 quarter-rows ----
    const int ri    = tid >> 2;                // 0..63
    const int m     = ri >> 5;                 // 0=alpha_inter, 1=beta_inter
    const int row   = ri & 31;
    const int sq    = tid & 3;
    const int wbase = m * 8192 + row * 256 + ((((2 * sq) ^ (row & 7))) << 4);

    float sum = 0.f;

    if (s <= jt) {
        const int ntiles = ((jt - s) >> 1) + 1;
        int ib = s * TI;

        // prolog: fill buf0, issue loads for buf1
        Stage rA = stage_load(binp, tb, ib, row, m, sq);
        stage_write(ldsc, wbase, rA);
        Stage rB = stage_load(binp, tb, ib + 32, row, m, sq);

        for (int t = 0; t < ntiles; ++t) {
            const int ibn   = ib + NS * TI;
            const bool more = (t + 1 < ntiles);

            // ---- even phase: compute buf0 (rows ib..ib+31) ----
            __syncthreads();                       // publishes buf0; odd compute of t-1 done
            stage_write(ldsc + 16384, wbase, rB);  // buf1 <- rows ib+32 (loads covered by prev phase)
            if (more) rA = stage_load(binp, tb, ibn, row, m, sq);   // issue early: full compute shadow
            sum += phase_compute(ldsc, binp, bfa, bfb, roff, ib, tj, quad);

            // ---- odd phase: compute buf1 (rows ib+32..ib+63) ----
            __syncthreads();                       // publishes buf1; even compute done
            if (more) {
                stage_write(ldsc, wbase, rA);      // buf0 <- next tile rows
                rB = stage_load(binp, tb, ibn + 32, row, m, sq);
            }
            sum += phase_compute(ldsc + 16384, binp, bfa, bfb, roff, ib + 32, tj, quad);

            ib = ibn;
        }
    }

    // reduce the 4 quads holding the same j
    sum += __shfl_xor(sum, 16, 64);
    sum += __shfl_xor(sum, 32, 64);

    if (quad == 0) {
        acc[(((long)s * NB + b) << 10) + jlane] = sum;   // write-once, no init needed
    }
}

extern "C" __global__ __launch_bounds__(256)
void hawkes_finalize(const int* __restrict__ inp, const float* __restrict__ pbase,
                     const float* __restrict__ sbase,
                     const float* __restrict__ ai, const float* __restrict__ as,
                     const float* __restrict__ bi, const float* __restrict__ bs,
                     const float* __restrict__ acc, float* __restrict__ out)
{
    const int t = blockIdx.x * 256 + threadIdx.x;   // 65536
    const int b = t >> 10, j = t & (SL - 1);
    const int* binp = inp + b * 4 * SL;
    const int tj   = binp[3 * SL + j];
    const int sk_j = binp[j];

    // exact fp32 correction for duplicate-timestamp pairs (adjacent in sorted order)
    float corr = 0.f;
    for (int i = j - 1; i >= 0 && binp[3 * SL + i] == tj; --i) {
        const int ski = binp[i], li = binp[2 * SL + i];
        const long intr = ski + (long)li * NSK;
        corr += fixup_pair(ai + intr * EMB, bi + intr * EMB,
                           as + (long)sk_j * EMB, bs + (long)sk_j * EMB);
    }

    float sum = acc[t] + acc[NB * SL + t] + corr;
    const float x = pbase[binp[SL + j]] + sbase[sk_j] + sum;
    out[t] = 1.f / (1.f + __expf(-x));
}

extern "C" void kernel_launch(void* const* d_in, const int* in_sizes, int n_in,
                              void* d_out, int out_size, void* d_ws, size_t ws_size,
                              hipStream_t stream) {
    const int*   inp = (const int*)d_in[0];
    const float* pb  = (const float*)d_in[1];
    const float* sb  = (const float*)d_in[2];
    const float* ai  = (const float*)d_in[3];
    const float* as  = (const float*)d_in[4];
    const float* bi  = (const float*)d_in[5];
    const float* bs  = (const float*)d_in[6];

    unsigned short* tb  = (unsigned short*)d_ws;
    float*          acc = (float*)((char*)d_ws + ACC_BYTE_OFF);

    cvt_tables<<<dim3(96000 / 256), dim3(256), 0, stream>>>(ai, bi, as, bs, tb);
    hawkes_main<<<dim3(NB * 16 * NS), dim3(256), 0, stream>>>(inp, tb, acc);
    hawkes_finalize<<<dim3(NB * SL / 256), dim3(256), 0, stream>>>(
        inp, pb, sb, ai, as, bi, bs, acc, (float*)d_out);
}